// Round 1
// baseline (579.538 us; speedup 1.0000x reference)
//
#include <hip/hip_runtime.h>
#include <hip/hip_bf16.h>
#include <cstdint>

#define DIM   768
#define HEADS 12
#define HD    64
#define NTOK  197
#define BATCH 64
#define MROWS (BATCH*NTOK)   /* 12608 */
#define MPAD  12672          /* 99*128 */
#define HIDN  3072
#define QSCALE 0.125f
#define LNEPS 1e-6f

typedef __bf16 bf16;
typedef __bf16 bf16x8 __attribute__((ext_vector_type(8)));
typedef __bf16 bf16x4 __attribute__((ext_vector_type(4)));
typedef float  f32x4  __attribute__((ext_vector_type(4)));

__device__ inline void gload_lds16(const void* src, void* dst) {
  __builtin_amdgcn_global_load_lds(
      (__attribute__((address_space(1))) void*)(src),
      (__attribute__((address_space(3))) void*)(dst), 16, 0, 0);
}

// ---------------- weight f32 -> bf16 convert ----------------
__global__ __launch_bounds__(256) void conv_kernel(const float* __restrict__ in,
                                                   bf16* __restrict__ out, int n4) {
  int i = blockIdx.x * 256 + threadIdx.x;
  if (i < n4) {
    float4 f = ((const float4*)in)[i];
    bf16x4 o; o.x = (bf16)f.x; o.y = (bf16)f.y; o.z = (bf16)f.z; o.w = (bf16)f.w;
    ((bf16x4*)out)[i] = o;
  }
}

// ---------------- relative position bias precompute: bias[h][i][j] ----------------
__global__ __launch_bounds__(256) void bias_kernel(const float* __restrict__ rh,
                                                   const float* __restrict__ rw,
                                                   const int* __restrict__ hidx,
                                                   const int* __restrict__ widx,
                                                   float* __restrict__ bias) {
  int idx = blockIdx.x * 256 + threadIdx.x;
  const int NN = NTOK * NTOK;
  if (idx >= HEADS * NN) return;
  int h  = idx / NN;
  int ij = idx - h * NN;
  bias[idx] = rh[hidx[ij] * HEADS + h] + rw[widx[ij] * HEADS + h];
}

// ---------------- LayerNorm f32 -> bf16 ----------------
__global__ __launch_bounds__(256) void ln_kernel(const float* __restrict__ x,
                                                 const float* __restrict__ w,
                                                 const float* __restrict__ b,
                                                 bf16* __restrict__ out) {
  int row = blockIdx.x;
  int tid = threadIdx.x;
  const float* xr = x + (size_t)row * DIM;
  float v0 = xr[tid], v1 = xr[tid + 256], v2 = xr[tid + 512];
  float s  = v0 + v1 + v2;
  float s2 = v0 * v0 + v1 * v1 + v2 * v2;
#pragma unroll
  for (int d = 1; d < 64; d <<= 1) { s += __shfl_xor(s, d); s2 += __shfl_xor(s2, d); }
  __shared__ float red[8];
  int wv = tid >> 6, ln = tid & 63;
  if (ln == 0) { red[wv] = s; red[wv + 4] = s2; }
  __syncthreads();
  s  = red[0] + red[1] + red[2] + red[3];
  s2 = red[4] + red[5] + red[6] + red[7];
  float mean = s * (1.0f / DIM);
  float var  = s2 * (1.0f / DIM) - mean * mean;
  float rs   = rsqrtf(var + LNEPS);
  bf16* outr = out + (size_t)row * DIM;
  outr[tid]       = (bf16)((v0 - mean) * rs * w[tid]       + b[tid]);
  outr[tid + 256] = (bf16)((v1 - mean) * rs * w[tid + 256] + b[tid + 256]);
  outr[tid + 512] = (bf16)((v2 - mean) * rs * w[tid + 512] + b[tid + 512]);
}

// ---------------- GEMM: C = A[M,K] * Bw[N,K]^T, fused epilogues ----------------
// EPI 0: qkv scatter (p0=q_bias, p1=v_bias, out bf16 qkv buffer)
// EPI 1: residual f32  (p0=bias, p1=residual f32, out f32, stride Ncols)
// EPI 2: gelu bf16     (p0=bias, out bf16, stride Ncols)
template <int EPI>
__global__ __launch_bounds__(256)
void gemm_bt(const bf16* __restrict__ A, const bf16* __restrict__ Bw,
             int K, int Ncols,
             const float* __restrict__ p0, const float* __restrict__ p1,
             void* __restrict__ outp) {
  __shared__ __align__(16) bf16 As[128 * 32];
  __shared__ __align__(16) bf16 Bs[128 * 32];
  const int tid  = threadIdx.x;
  const int wave = tid >> 6, lane = tid & 63;
  const int wm = wave >> 1, wn = wave & 1;
  const int rowBase = blockIdx.y * 128;
  const int colBase = blockIdx.x * 128;
  const int l4 = lane >> 2, c8 = (lane & 3) * 8;

  f32x4 acc[4][4] = {};

  int ra0 = rowBase + wave * 16 + l4;
  int ra1 = ra0 + 64;
  int ca0 = ra0 > (MROWS - 1) ? (MROWS - 1) : ra0;
  int ca1 = ra1 > (MROWS - 1) ? (MROWS - 1) : ra1;
  const bf16* gA0 = A + (size_t)ca0 * K + c8;
  const bf16* gA1 = A + (size_t)ca1 * K + c8;
  const bf16* gB0 = Bw + (size_t)(colBase + wave * 16 + l4) * K + c8;
  const bf16* gB1 = gB0 + (size_t)64 * K;
  bf16* lA0 = &As[(wave * 16) * 32];
  bf16* lA1 = &As[(64 + wave * 16) * 32];
  bf16* lB0 = &Bs[(wave * 16) * 32];
  bf16* lB1 = &Bs[(64 + wave * 16) * 32];

  const int lr = lane & 15, lk = (lane >> 4) * 8;

  for (int kt = 0; kt < K; kt += 32) {
    gload_lds16(gA0 + kt, lA0);
    gload_lds16(gA1 + kt, lA1);
    gload_lds16(gB0 + kt, lB0);
    gload_lds16(gB1 + kt, lB1);
    __syncthreads();
    bf16x8 af[4], bfv[4];
#pragma unroll
    for (int m = 0; m < 4; ++m)
      af[m] = *(const bf16x8*)&As[(wm * 64 + m * 16 + lr) * 32 + lk];
#pragma unroll
    for (int n = 0; n < 4; ++n)
      bfv[n] = *(const bf16x8*)&Bs[(wn * 64 + n * 16 + lr) * 32 + lk];
#pragma unroll
    for (int m = 0; m < 4; ++m)
#pragma unroll
      for (int n = 0; n < 4; ++n)
        acc[m][n] = __builtin_amdgcn_mfma_f32_16x16x32_bf16(af[m], bfv[n], acc[m][n], 0, 0, 0);
    __syncthreads();
  }

  const int rlane = (lane >> 4) * 4;
  const int clane = lane & 15;
#pragma unroll
  for (int m = 0; m < 4; ++m) {
#pragma unroll
    for (int n = 0; n < 4; ++n) {
#pragma unroll
      for (int r = 0; r < 4; ++r) {
        int row = rowBase + wm * 64 + m * 16 + rlane + r;
        int col = colBase + wn * 64 + n * 16 + clane;
        if (row >= MROWS) continue;
        float v = acc[m][n][r];
        if constexpr (EPI == 0) {
          int which = col / DIM;
          int jj = col - which * DIM;
          if (which == 0) v = (v + p0[jj]) * QSCALE;
          else if (which == 2) v = v + p1[jj];
          int bb = row / NTOK, nt = row - bb * NTOK;
          int h = jj >> 6, hd = jj & 63;
          ((bf16*)outp)[((size_t)(which * 768 + bb * HEADS + h) * NTOK + nt) * 64 + hd] = (bf16)v;
        } else if constexpr (EPI == 1) {
          ((float*)outp)[(size_t)row * Ncols + col] =
              p1[(size_t)row * Ncols + col] + v + p0[col];
        } else {
          float t = v + p0[col];
          float g = 0.5f * t * (1.0f + erff(t * 0.70710678118654752f));
          ((bf16*)outp)[(size_t)row * Ncols + col] = (bf16)g;
        }
      }
    }
  }
}

// ---------------- fused attention: one block per (b,h) ----------------
__global__ __launch_bounds__(256)
void attn_kernel(const bf16* __restrict__ qkv, const float* __restrict__ bias,
                 bf16* __restrict__ out) {
  const int bh = blockIdx.x;
  const int b = bh / HEADS, h = bh - b * HEADS;
  const bf16* qg = qkv + (size_t)bh * NTOK * HD;
  const bf16* kg = qg + (size_t)768 * NTOK * HD;
  const bf16* vg = qg + (size_t)1536 * NTOK * HD;

  __shared__ __align__(16) bf16 Ks[224 * 64];
  __shared__ __align__(16) bf16 Vt[64 * 224];
  __shared__ __align__(16) bf16 Ps[4][16 * 32];

  const int tid = threadIdx.x;
  // stage K rows 0..196 (contiguous copy)
  for (int i = tid; i < (NTOK * HD) / 8; i += 256)
    ((uint4*)Ks)[i] = ((const uint4*)kg)[i];
  // stage V transposed: Vt[d][j]
  for (int i = tid; i < NTOK * HD; i += 256) {
    int j = i >> 6, d = i & 63;
    Vt[d * 224 + j] = vg[i];
  }
  // zero V pad columns j in [197,224)
  for (int i = tid; i < 64 * 27; i += 256) {
    int d = i / 27, j = 197 + (i - d * 27);
    Vt[d * 224 + j] = (bf16)0.0f;
  }
  __syncthreads();

  const int wave = tid >> 6, lane = tid & 63;
  const int lr = lane & 15, lg = lane >> 4;
  const int tstart = (wave == 0) ? 0 : 1 + wave * 3;   // 0,4,7,10
  const int tcount = (wave == 0) ? 4 : 3;
  const float* bh_bias = bias + (size_t)h * NTOK * NTOK;

  for (int ti = 0; ti < tcount; ++ti) {
    const int mi = tstart + ti;
    int qrow = mi * 16 + lr; if (qrow > NTOK - 1) qrow = NTOK - 1;
    bf16x8 aq0 = *(const bf16x8*)(qg + (size_t)qrow * 64 + lg * 8);
    bf16x8 aq1 = *(const bf16x8*)(qg + (size_t)qrow * 64 + 32 + lg * 8);

    f32x4 sacc[14];
#pragma unroll
    for (int nj = 0; nj < 14; ++nj) {
      bf16x8 bk0 = *(const bf16x8*)&Ks[(nj * 16 + lr) * 64 + lg * 8];
      bf16x8 bk1 = *(const bf16x8*)&Ks[(nj * 16 + lr) * 64 + 32 + lg * 8];
      f32x4 c = {};
      c = __builtin_amdgcn_mfma_f32_16x16x32_bf16(aq0, bk0, c, 0, 0, 0);
      c = __builtin_amdgcn_mfma_f32_16x16x32_bf16(aq1, bk1, c, 0, 0, 0);
      sacc[nj] = c;
    }

    float rowinv[4];
#pragma unroll
    for (int r = 0; r < 4; ++r) {
      int i = mi * 16 + lg * 4 + r;
      int iv = i < NTOK ? i : NTOK - 1;
      float mloc = -1e30f;
#pragma unroll
      for (int nj = 0; nj < 14; ++nj) {
        int j = nj * 16 + lr;
        float sv;
        if (j < NTOK) sv = sacc[nj][r] + bh_bias[(size_t)iv * NTOK + j];
        else sv = -1e30f;
        sacc[nj][r] = sv;
        mloc = fmaxf(mloc, sv);
      }
#pragma unroll
      for (int d = 1; d < 16; d <<= 1) mloc = fmaxf(mloc, __shfl_xor(mloc, d));
      float lloc = 0.f;
#pragma unroll
      for (int nj = 0; nj < 14; ++nj) {
        float p = __expf(sacc[nj][r] - mloc);
        sacc[nj][r] = p;
        lloc += p;
      }
#pragma unroll
      for (int d = 1; d < 16; d <<= 1) lloc += __shfl_xor(lloc, d);
      rowinv[r] = 1.0f / lloc;
    }

    // PV: chunk P (16x32) through wave-private LDS, MFMA against Vt
    f32x4 oacc[4] = {};
    bf16* myPs = &Ps[wave][0];
#pragma unroll 1
    for (int kt = 0; kt < 7; ++kt) {
#pragma unroll
      for (int half = 0; half < 2; ++half) {
        int nj = kt * 2 + half;
#pragma unroll
        for (int r = 0; r < 4; ++r)
          myPs[(lg * 4 + r) * 32 + half * 16 + lr] = (bf16)sacc[nj][r];
      }
      asm volatile("s_waitcnt lgkmcnt(0)" ::: "memory");
      __builtin_amdgcn_sched_barrier(0);
      bf16x8 pa = *(const bf16x8*)&myPs[lr * 32 + lg * 8];
#pragma unroll
      for (int nd = 0; nd < 4; ++nd) {
        bf16x8 bv = *(const bf16x8*)&Vt[(nd * 16 + lr) * 224 + kt * 32 + lg * 8];
        oacc[nd] = __builtin_amdgcn_mfma_f32_16x16x32_bf16(pa, bv, oacc[nd], 0, 0, 0);
      }
      asm volatile("s_waitcnt lgkmcnt(0)" ::: "memory");
      __builtin_amdgcn_sched_barrier(0);
    }

#pragma unroll
    for (int nd = 0; nd < 4; ++nd)
#pragma unroll
      for (int r = 0; r < 4; ++r) {
        int i = mi * 16 + lg * 4 + r;
        if (i < NTOK) {
          int d = nd * 16 + lr;
          out[((size_t)(b * NTOK + i)) * DIM + h * 64 + d] = (bf16)(oacc[nd][r] * rowinv[r]);
        }
      }
  }
}

// ---------------- launch ----------------
extern "C" void kernel_launch(void* const* d_in, const int* in_sizes, int n_in,
                              void* d_out, int out_size, void* d_ws, size_t ws_size,
                              hipStream_t stream) {
  const float* x    = (const float*)d_in[0];
  const float* n1w  = (const float*)d_in[1];
  const float* n1b  = (const float*)d_in[2];
  const float* qkvw = (const float*)d_in[3];
  const float* qb   = (const float*)d_in[4];
  const float* vb   = (const float*)d_in[5];
  const float* pw   = (const float*)d_in[6];
  const float* pb   = (const float*)d_in[7];
  const float* rh   = (const float*)d_in[8];
  const float* rw   = (const float*)d_in[9];
  const float* n2w  = (const float*)d_in[10];
  const float* n2b  = (const float*)d_in[11];
  const float* f1w  = (const float*)d_in[12];
  const float* f1b  = (const float*)d_in[13];
  const float* f2w  = (const float*)d_in[14];
  const float* f2b  = (const float*)d_in[15];
  const int* hidx   = (const int*)d_in[16];
  const int* widx   = (const int*)d_in[17];

  char* ws = (char*)d_ws;
  size_t off = 0;
  auto alloc = [&](size_t bytes) {
    void* p = ws + off;
    off += (bytes + 255) & ~(size_t)255;
    return p;
  };
  bf16* wqkv  = (bf16*)alloc((size_t)2304 * 768 * 2);
  bf16* wproj = (bf16*)alloc((size_t)768 * 768 * 2);
  bf16* wfc1  = (bf16*)alloc((size_t)3072 * 768 * 2);
  bf16* wfc2  = (bf16*)alloc((size_t)768 * 3072 * 2);
  float* biasT = (float*)alloc((size_t)HEADS * NTOK * NTOK * 4);
  bf16* hbf = (bf16*)alloc((size_t)MPAD * 768 * 2);
  float* x1 = (float*)alloc((size_t)MROWS * 768 * 4);
  bf16* qkv   = (bf16*)alloc((size_t)3 * 768 * NTOK * 64 * 2);
  bf16* attno = (bf16*)alloc((size_t)MROWS * 768 * 2);
  bf16* mbuf  = qkv;  // reuse qkv+attno region (exact size match 12608*3072*2)

  conv_kernel<<<(2304 * 768 / 4 + 255) / 256, 256, 0, stream>>>(qkvw, wqkv, 2304 * 768 / 4);
  conv_kernel<<<(768 * 768 / 4 + 255) / 256, 256, 0, stream>>>(pw, wproj, 768 * 768 / 4);
  conv_kernel<<<(3072 * 768 / 4 + 255) / 256, 256, 0, stream>>>(f1w, wfc1, 3072 * 768 / 4);
  conv_kernel<<<(768 * 3072 / 4 + 255) / 256, 256, 0, stream>>>(f2w, wfc2, 768 * 3072 / 4);
  bias_kernel<<<(HEADS * NTOK * NTOK + 255) / 256, 256, 0, stream>>>(rh, rw, hidx, widx, biasT);

  ln_kernel<<<MROWS, 256, 0, stream>>>(x, n1w, n1b, hbf);
  gemm_bt<0><<<dim3(2304 / 128, MPAD / 128), 256, 0, stream>>>(hbf, wqkv, 768, 2304, qb, vb, qkv);
  attn_kernel<<<768, 256, 0, stream>>>(qkv, biasT, attno);
  gemm_bt<1><<<dim3(768 / 128, MPAD / 128), 256, 0, stream>>>(attno, wproj, 768, 768, pb, x, x1);
  ln_kernel<<<MROWS, 256, 0, stream>>>(x1, n2w, n2b, hbf);
  gemm_bt<2><<<dim3(3072 / 128, MPAD / 128), 256, 0, stream>>>(hbf, wfc1, 768, 3072, f1b, nullptr, mbuf);
  gemm_bt<1><<<dim3(768 / 128, MPAD / 128), 256, 0, stream>>>(mbuf, wfc2, 3072, 768, f2b, x1, d_out);
}